// Round 1
// baseline (546.948 us; speedup 1.0000x reference)
//
#include <hip/hip_runtime.h>
#include <math.h>

#define NNODES 200000
#define NG 1000
#define NPG 200
#define KNN 5
#define MD 128

// ---------------- kNN: one block per graph ----------------
__global__ __launch_bounds__(256) void knn_kernel(const float* __restrict__ pos,
                                                  int* __restrict__ knn) {
  __shared__ float sp[NPG * 3];
  int g = blockIdx.x;
  int t = threadIdx.x;
  for (int i = t; i < NPG * 3; i += 256) sp[i] = pos[(size_t)g * NPG * 3 + i];
  __syncthreads();
  if (t < NPG) {
    float x = sp[t * 3 + 0], y = sp[t * 3 + 1], z = sp[t * 3 + 2];
    float bd[KNN];
    int bi[KNN];
#pragma unroll
    for (int k = 0; k < KNN; k++) { bd[k] = 3.0e38f; bi[k] = 0; }
    for (int j = 0; j < NPG; j++) {
      if (j == t) continue;
      // match numpy: (dx*dx + dy*dy) + dz*dz, no FMA contraction
      float dx = __fsub_rn(x, sp[j * 3 + 0]);
      float dy = __fsub_rn(y, sp[j * 3 + 1]);
      float dz = __fsub_rn(z, sp[j * 3 + 2]);
      float d2 = __fadd_rn(__fadd_rn(__fmul_rn(dx, dx), __fmul_rn(dy, dy)),
                           __fmul_rn(dz, dz));
      if (d2 < bd[KNN - 1]) {  // strict <: ties keep lower index (top_k stable)
        bd[KNN - 1] = d2; bi[KNN - 1] = j;
#pragma unroll
        for (int k = KNN - 1; k > 0; k--) {
          if (bd[k] < bd[k - 1]) {
            float td = bd[k]; bd[k] = bd[k - 1]; bd[k - 1] = td;
            int ti = bi[k]; bi[k] = bi[k - 1]; bi[k - 1] = ti;
          }
        }
      }
    }
#pragma unroll
    for (int k = 0; k < KNN; k++)
      knn[((size_t)g * NPG + t) * KNN + k] = g * NPG + bi[k];
  }
}

// ---------------- embW0 = emb @ W0 (100x128 @ 128x128) ----------------
__global__ __launch_bounds__(256) void emb_gemm_kernel(const float* __restrict__ emb,
                                                       const float* __restrict__ W,
                                                       float* __restrict__ embW) {
  int idx = blockIdx.x * 256 + threadIdx.x;  // 12800 total
  int r = idx >> 7, c = idx & 127;
  float a = 0.0f;
  for (int k = 0; k < MD; k++) a += emb[r * MD + k] * W[k * MD + c];
  embW[idx] = a;
}

// ---------------- layer 1: gather from embW0 table ----------------
__global__ __launch_bounds__(256) void layer1_kernel(const int* __restrict__ z,
                                                     const int* __restrict__ knn,
                                                     const float* __restrict__ embW,
                                                     const float* __restrict__ b,
                                                     float* __restrict__ xout) {
  int node = blockIdx.x * 2 + (threadIdx.x >> 7);
  int c = threadIdx.x & 127;
  const float dis = 1.0f / sqrtf(6.0f);
  const float s6 = dis * dis;
  const int* kn = knn + (size_t)node * KNN;
  int zi = z[node];
  int z0 = z[kn[0]], z1 = z[kn[1]], z2 = z[kn[2]], z3 = z[kn[3]], z4 = z[kn[4]];
  float m = embW[(size_t)z0 * MD + c] * s6;
  m += embW[(size_t)z1 * MD + c] * s6;
  m += embW[(size_t)z2 * MD + c] * s6;
  m += embW[(size_t)z3 * MD + c] * s6;
  m += embW[(size_t)z4 * MD + c] * s6;
  m += embW[(size_t)zi * MD + c] * s6;  // self-loop term
  float v = m + b[c];
  xout[(size_t)node * MD + c] = fmaxf(v, 0.0f);
}

// ---------------- fp32 GEMM: C[N x128] = A[N x128] @ B[128 x128] ----------------
// block 256 threads, BM=64 rows, BN=128 cols, BK=16
__global__ __launch_bounds__(256) void gemm_kernel(const float* __restrict__ A,
                                                   const float* __restrict__ B,
                                                   float* __restrict__ C) {
  __shared__ float As[16][64];
  __shared__ float Bs[16][128];
  int tid = threadIdx.x;
  int row0 = blockIdx.x * 64;
  int tx = tid & 15;   // col group: cols tx*8 .. +7
  int ty = tid >> 4;   // row group: rows ty*4 .. +3
  float acc[4][8];
#pragma unroll
  for (int i = 0; i < 4; i++)
#pragma unroll
    for (int j = 0; j < 8; j++) acc[i][j] = 0.0f;

  int lm = tid >> 2, lk = (tid & 3) << 2;        // A-tile load: 64x16, one float4/thread
  int lbk = tid >> 5, lbn = (tid & 31) << 2;     // B-tile load: 16x128, two float4/thread

  for (int k0 = 0; k0 < MD; k0 += 16) {
    float4 av = *(const float4*)(A + (size_t)(row0 + lm) * MD + k0 + lk);
    float4 bv0 = *(const float4*)(B + (size_t)(k0 + lbk) * MD + lbn);
    float4 bv1 = *(const float4*)(B + (size_t)(k0 + lbk + 8) * MD + lbn);
    As[lk + 0][lm] = av.x;
    As[lk + 1][lm] = av.y;
    As[lk + 2][lm] = av.z;
    As[lk + 3][lm] = av.w;
    *(float4*)(&Bs[lbk][lbn]) = bv0;
    *(float4*)(&Bs[lbk + 8][lbn]) = bv1;
    __syncthreads();
#pragma unroll
    for (int kk = 0; kk < 16; kk++) {
      float4 a4 = *(const float4*)(&As[kk][ty * 4]);
      float4 b4a = *(const float4*)(&Bs[kk][tx * 8]);
      float4 b4b = *(const float4*)(&Bs[kk][tx * 8 + 4]);
      float a[4] = {a4.x, a4.y, a4.z, a4.w};
      float b[8] = {b4a.x, b4a.y, b4a.z, b4a.w, b4b.x, b4b.y, b4b.z, b4b.w};
#pragma unroll
      for (int i = 0; i < 4; i++)
#pragma unroll
        for (int j = 0; j < 8; j++) acc[i][j] += a[i] * b[j];
    }
    __syncthreads();
  }
#pragma unroll
  for (int i = 0; i < 4; i++) {
    size_t row = row0 + ty * 4 + i;
    *(float4*)(C + row * MD + tx * 8) =
        make_float4(acc[i][0], acc[i][1], acc[i][2], acc[i][3]);
    *(float4*)(C + row * MD + tx * 8 + 4) =
        make_float4(acc[i][4], acc[i][5], acc[i][6], acc[i][7]);
  }
}

// ---------------- aggregation + relu (layers 2,3) ----------------
__global__ __launch_bounds__(256) void agg_kernel(const float* __restrict__ h,
                                                  const int* __restrict__ knn,
                                                  const float* __restrict__ b,
                                                  float* __restrict__ xout) {
  int node = blockIdx.x * 2 + (threadIdx.x >> 7);
  int c = threadIdx.x & 127;
  const float dis = 1.0f / sqrtf(6.0f);
  const float s6 = dis * dis;
  const int* kn = knn + (size_t)node * KNN;
  int j0 = kn[0], j1 = kn[1], j2 = kn[2], j3 = kn[3], j4 = kn[4];
  float m = h[(size_t)j0 * MD + c] * s6;
  m += h[(size_t)j1 * MD + c] * s6;
  m += h[(size_t)j2 * MD + c] * s6;
  m += h[(size_t)j3 * MD + c] * s6;
  m += h[(size_t)j4 * MD + c] * s6;
  m += h[(size_t)node * MD + c] * s6;  // self loop
  float v = m + b[c];
  xout[(size_t)node * MD + c] = fmaxf(v, 0.0f);
}

// ---------------- mean-pool + MLP: one block (128 thr) per graph ----------------
__global__ __launch_bounds__(128) void pool_mlp_kernel(const float* __restrict__ x,
                                                       const float* __restrict__ rW1,
                                                       const float* __restrict__ rb1,
                                                       const float* __restrict__ rW2,
                                                       const float* __restrict__ rb2,
                                                       const float* __restrict__ rW3,
                                                       const float* __restrict__ rb3,
                                                       float* __restrict__ out) {
  __shared__ float pooled[128];
  __shared__ float h1[64];
  __shared__ float h2[32];
  int g = blockIdx.x;
  int t = threadIdx.x;
  const float* xg = x + (size_t)g * NPG * MD;
  float s = 0.0f;
  for (int n = 0; n < NPG; n++) s += xg[(size_t)n * MD + t];
  pooled[t] = s / 200.0f;
  __syncthreads();
  if (t < 64) {
    float a = rb1[t];
    for (int c = 0; c < 128; c++) a += pooled[c] * rW1[c * 64 + t];
    h1[t] = fmaxf(a, 0.0f);
  }
  __syncthreads();
  if (t < 32) {
    float a = rb2[t];
    for (int c = 0; c < 64; c++) a += h1[c] * rW2[c * 32 + t];
    h2[t] = fmaxf(a, 0.0f);
  }
  __syncthreads();
  if (t == 0) {
    float a = rb3[0];
    for (int c = 0; c < 32; c++) a += h2[c] * rW3[c];
    out[g] = a;
  }
}

extern "C" void kernel_launch(void* const* d_in, const int* in_sizes, int n_in,
                              void* d_out, int out_size, void* d_ws, size_t ws_size,
                              hipStream_t stream) {
  const int* z = (const int*)d_in[0];
  const float* pos = (const float*)d_in[1];
  // d_in[2] = batch (implicit: node/200)
  const float* emb = (const float*)d_in[3];
  const float* convW = (const float*)d_in[4];   // [3][128][128]
  const float* convb = (const float*)d_in[5];   // [3][128]
  const float* rW1 = (const float*)d_in[6];
  const float* rb1 = (const float*)d_in[7];
  const float* rW2 = (const float*)d_in[8];
  const float* rb2 = (const float*)d_in[9];
  const float* rW3 = (const float*)d_in[10];
  const float* rb3 = (const float*)d_in[11];
  float* out = (float*)d_out;

  char* ws = (char*)d_ws;
  int* knn = (int*)ws;                                        // 4,000,000 B
  float* xbuf = (float*)(ws + 4000000);                       // 102,400,000 B
  float* hbuf = (float*)(ws + 4000000 + 102400000);           // 102,400,000 B
  float* embW = (float*)(ws + 4000000 + 2 * 102400000ULL);    // 51,200 B

  knn_kernel<<<NG, 256, 0, stream>>>(pos, knn);
  emb_gemm_kernel<<<50, 256, 0, stream>>>(emb, convW, embW);
  layer1_kernel<<<NNODES / 2, 256, 0, stream>>>(z, knn, embW, convb, xbuf);
  for (int l = 1; l < 3; l++) {
    gemm_kernel<<<NNODES / 64, 256, 0, stream>>>(xbuf, convW + (size_t)l * MD * MD, hbuf);
    agg_kernel<<<NNODES / 2, 256, 0, stream>>>(hbuf, knn, convb + (size_t)l * MD, xbuf);
  }
  pool_mlp_kernel<<<NG, 128, 0, stream>>>(xbuf, rW1, rb1, rW2, rb2, rW3, rb3, out);
}